// Round 12
// baseline (456.361 us; speedup 1.0000x reference)
//
#include <hip/hip_runtime.h>
#include <stdint.h>

#define TOKENS 8192
#define DM     1024
#define VOCAB  32000
#define BM     128
#define BN     128
#define NITER  8            // 8 iters x 2 k-blocks of 64 (K = 1024)

#define SCALE   64.0f
#define INV_S2  2.44140625e-4f   // 1/(SCALE*SCALE)
#define A_BYTES ((size_t)TOKENS * DM / 2)

#define CVT_BLOCKS ((TOKENS + VOCAB) * (DM / 32) / 256)   // 5024
#define TSC_BLOCKS (TOKENS / 4)                           // 2048

typedef int   i32x4  __attribute__((ext_vector_type(4)));
typedef int   i32x8  __attribute__((ext_vector_type(8)));
typedef float f32x4  __attribute__((ext_vector_type(4)));
typedef float f32x16 __attribute__((ext_vector_type(16)));

// g_P4: x then W in fp4 e2m1 (scaled x64), tiled slot-order layout.
// For 32-row group R, 64-k block K, slot u in [0,64):
//   chunk addr = R*16384 + K*1024 + u*16 bytes, u = h*32 + r
//   content    = row R*32+r, k-elements [K*64 + h*32, +32), nibble j = element j
// Verified (absmax 0, rounds 0-11). Chunks are lane-linear: a direct
// global_load_dwordx4 IS an MFMA fragment; contiguous copy IS LDS staging.
//
// Session model at 167us (r10/r11): NO pipe saturated (TCP 56%, LDS 35%,
// MFMA 38%, HBM 6%) -> latency equilibrium: ~16 waves/CU queue on TCP,
// effective load latency ~2-3k cyc, 1-iter issue-to-use distance gives
// exactly ~1 iter of cover -> ~38% duty cycle. r8's depth-2 probe was
// unpinned (compiler free to sink loads -> effective depth 1). This round:
// B in 3 register slots with asm-PINNED 2-iter distance; A already 2-iter
// via LDS triple-buffer; counted s_waitcnt vmcnt(6) keeps 6 loads in
// flight across the barrier.
__device__ __align__(16) unsigned char g_P4[(size_t)(TOKENS + VOCAB) * DM / 2];
__device__ float g_S[TOKENS];   // sum exp(logit); logits ~ +-0.1 -> no max shift
__device__ float g_T[TOKENS];   // target score (exact fp32)

// Fallback RTN to e2m1 grid {0,.5,1,1.5,2,3,4,6} after x64 scale.
__device__ __forceinline__ unsigned q4(float x) {
  float a = fabsf(x) * SCALE;
  unsigned n = (unsigned)(a >= 0.25f) + (a >= 0.75f) + (a >= 1.25f) + (a >= 1.75f)
             + (a >= 2.5f) + (a >= 3.5f) + (a >= 5.0f);
  return n | ((x < 0.0f) ? 8u : 0u);
}

#if __has_builtin(__builtin_amdgcn_cvt_scalef32_pk_fp4_f32)
// HW path (verified r7-r11, absmax 0): one VALU op packs 2 f32 -> 2 e2m1 nibbles.
__device__ __forceinline__ unsigned pk8(const float4 a, const float4 b) {
  unsigned w = 0;
  w = __builtin_amdgcn_cvt_scalef32_pk_fp4_f32(w, a.x * SCALE, a.y * SCALE, 1.0f, 0);
  w = __builtin_amdgcn_cvt_scalef32_pk_fp4_f32(w, a.z * SCALE, a.w * SCALE, 1.0f, 1);
  w = __builtin_amdgcn_cvt_scalef32_pk_fp4_f32(w, b.x * SCALE, b.y * SCALE, 1.0f, 2);
  w = __builtin_amdgcn_cvt_scalef32_pk_fp4_f32(w, b.z * SCALE, b.w * SCALE, 1.0f, 3);
  return w;
}
#else
__device__ __forceinline__ unsigned pk8(const float4 a, const float4 b) {
  return  q4(a.x)        | (q4(a.y) << 4)  | (q4(a.z) << 8)  | (q4(a.w) << 12)
       | (q4(b.x) << 16) | (q4(b.y) << 20) | (q4(b.z) << 24) | (q4(b.w) << 28);
}
#endif

// Fused cvt_fp4 + tscore (independent inputs; verified r6-r11). Blocks
// [0, CVT_BLOCKS) = cvt; [CVT_BLOCKS, +TSC_BLOCKS) = tscore.
__global__ __launch_bounds__(256) void cvt_tscore(const float4* __restrict__ X,
                                                  const float4* __restrict__ W,
                                                  const int* __restrict__ target) {
  if (blockIdx.x < CVT_BLOCKS) {
    // Thread = one 16B output chunk = 32 consecutive input floats (128B
    // contiguous read, fully-sequential 16B write). Also zeroes g_S.
    const unsigned c  = blockIdx.x * 256 + threadIdx.x;      // global chunk idx
    const unsigned AC = (unsigned)TOKENS * (DM / 32);        // 262144 A-chunks
    const float4* src;
    unsigned lc;
    if (c < AC) { src = X; lc = c; } else { src = W; lc = c - AC; }
    const unsigned R  = lc >> 10;          // 1024 chunks per 32-row group
    const unsigned kb = (lc >> 6) & 15;    // k-block
    const unsigned u  = lc & 63;
    const unsigned row = R * 32 + (u & 31);
    const float4* p = src + (size_t)row * (DM / 4) + kb * 16 + (u >> 5) * 8;
    uint4 r;
    r.x = pk8(p[0], p[1]);
    r.y = pk8(p[2], p[3]);
    r.z = pk8(p[4], p[5]);
    r.w = pk8(p[6], p[7]);
    ((uint4*)g_P4)[c] = r;
    if (c < TOKENS) g_S[c] = 0.0f;
  } else {
    // tscore (verified rounds 0-11): one wave per token, exact fp32.
    const int wave  = threadIdx.x >> 6;
    const int lane  = threadIdx.x & 63;
    const int token = (blockIdx.x - CVT_BLOCKS) * 4 + wave;
    const int tgt   = target[token];
    const float* Xs = (const float*)X;
    const float* Ws = (const float*)W;
    const float4* xr = (const float4*)(Xs + (size_t)token * DM);
    const float4* wr = (const float4*)(Ws + (size_t)tgt * DM);
    float acc = 0.0f;
#pragma unroll
    for (int i = 0; i < 4; ++i) {
      float4 a = xr[i * 64 + lane];
      float4 b = wr[i * 64 + lane];
      acc += a.x * b.x + a.y * b.y + a.z * b.z + a.w * b.w;
    }
#pragma unroll
    for (int m = 1; m <= 32; m <<= 1) acc += __shfl_xor(acc, m);
    if (lane == 0) g_T[token] = acc;
  }
}

// MX-fp4 GEMM: 128x128 block, 4 waves of 64x64 (2x2 of 32x32),
// mfma_scale_f32_32x32x64_f8f6f4 FMT=fp4 (unit scales).
// Split-pipe delivery (r10) + DEPTH-2 pinned pipeline on BOTH operands:
//   A: LDS triple-buffer via global_load_lds, staged 2 iters ahead.
//   B: 3 rotating register slots, loaded 2 iters ahead (asm-pinned order).
//   Per iter: raw s_barrier + s_waitcnt vmcnt(6) -- outstanding oldest->
//   newest = [B(it)4, A(it)2, B(it+1)4, A(it+1)2]; retire oldest 6, keep
//   6 in flight across the barrier. Full drain only at the last iter.
// Hazard: A buffer (it+2)%3 written while it%3 read, (it+1)%3 pending --
// disjoint mod 3; same for B slots. One barrier/iter suffices (verified
// structure r11, absmax 0).
__global__ __launch_bounds__(256, 4) void mevo_gemm() {
  // [0,24K): A triple-buffer (3 x 4 groups x 2 kb x 1KB).
  // Epilogue reuses all 32KB (4 x 8KB wave-private) after the final barrier.
  __shared__ __align__(16) unsigned char smem[32768];

  const int tid  = threadIdx.x;
  const int wave = tid >> 6;
  const int lane = tid & 63;

  const int bm = blockIdx.x & 63;    // consecutive blocks share bn -> B L2 reuse
  const int bn = blockIdx.x >> 6;    // (natural order is XCD-optimal: XCD=bm%8)

  const int tAbase = (wave >> 1) * 2;   // wave's two 32-row A groups
  const int tBbase = (wave & 1) * 2;    // wave's two 32-col B groups

  // A staging source: thread covers group tid>>6, slot tid&63 (contiguous
  // copy; LDS dst = wave-uniform base + lane*16 as gload_lds requires).
  const unsigned char* sA = g_P4 + ((size_t)(bm * 4 + (tid >> 6)) << 14) + (tid & 63) * 16;
  // B fragment streams (lane-linear, coalesced).
  const unsigned char* pB0 = g_P4 + A_BYTES + ((size_t)(bn * 4 + tBbase) << 14) + lane * 16;
  const unsigned char* pB1 = pB0 + 16384;

  f32x16 acc[2][2] = {};

#define STAGE_A(buf, koff)                                                          \
  do {                                                                              \
    unsigned char* lb = smem + (buf) * 8192;                                        \
    __builtin_amdgcn_global_load_lds(                                               \
        (const __attribute__((address_space(1))) void*)(sA + (koff)),               \
        (__attribute__((address_space(3))) void*)(lb + tid * 16), 16, 0, 0);        \
    __builtin_amdgcn_global_load_lds(                                               \
        (const __attribute__((address_space(1))) void*)(sA + (koff) + 1024),        \
        (__attribute__((address_space(3))) void*)(lb + 4096 + tid * 16), 16, 0, 0); \
  } while (0)

#define LOAD_B(slot, koff)                                                  \
  do {                                                                      \
    b[slot][0][0] = *(const i32x4*)(pB0 + (koff));                          \
    b[slot][0][1] = *(const i32x4*)(pB1 + (koff));                          \
    b[slot][1][0] = *(const i32x4*)(pB0 + (koff) + 1024);                   \
    b[slot][1][1] = *(const i32x4*)(pB1 + (koff) + 1024);                   \
  } while (0)

// undef-hi operand widen: fp4 (cbsz/blgp=4) reads only regs 0-3 of the 8-reg
// operand; undef hi lets regalloc alias without dup v_movs.
#define SHUF8U(v) __builtin_shufflevector((v), (v), 0, 1, 2, 3, -1, -1, -1, -1)
#define MFMA1(Av, Bv, mt, nt)                                               \
  acc[mt][nt] = __builtin_amdgcn_mfma_scale_f32_32x32x64_f8f6f4(            \
      (Av), (Bv), acc[mt][nt], 4, 4, 0, 0x7F7F7F7F, 0, 0x7F7F7F7F)

  i32x4 b[3][2][2];   // [slot][kb-parity][nt]; static after full unroll

  // Prologue, issue order PINNED: B(0), A(0), B(1), A(1) -> outstanding
  // oldest->newest = [B0 x4, A0 x2, B1 x4, A1 x2] (12 loads).
  LOAD_B(0, 0);
  asm volatile("" ::: "memory");
  STAGE_A(0, 0);
  asm volatile("" ::: "memory");
  LOAD_B(1, 2048);
  asm volatile("" ::: "memory");
  STAGE_A(1, 2048);

#pragma unroll
  for (int it = 0; it < NITER; ++it) {
    // Counted wait: retire B(it)+A(it) (oldest 6), keep B(it+1)+A(it+1)
    // (6 newest) in flight across the barrier. Steady state, prologue, and
    // tails (it=6: no new issues, 12 outstanding -> vmcnt(6) ok; it=7: only
    // 6 outstanding -> vmcnt(0) drains) verified by hand.
    if (it < NITER - 1) asm volatile("s_waitcnt vmcnt(6)" ::: "memory");
    else                asm volatile("s_waitcnt vmcnt(0)" ::: "memory");
    __builtin_amdgcn_s_barrier();
    asm volatile("" ::: "memory");

    // Issue iter it+2's loads: B FIRST, then A (order pinned so the vmcnt
    // arithmetic above stays valid).
    if (it + 2 < NITER) {
      LOAD_B((it + 2) % 3, (it + 2) * 2048);
      asm volatile("" ::: "memory");
      STAGE_A((it + 2) % 3, (it + 2) * 2048);
      asm volatile("" ::: "memory");
    }

    const unsigned char* Ab = smem + (it % 3) * 8192;
    const int cs = it % 3;
#pragma unroll
    for (int p = 0; p < 2; ++p) {
      i32x4 a0 = *(const i32x4*)(Ab + p * 4096 + (tAbase + 0) * 1024 + lane * 16);
      i32x4 a1 = *(const i32x4*)(Ab + p * 4096 + (tAbase + 1) * 1024 + lane * 16);
      i32x8 A0 = SHUF8U(a0), A1 = SHUF8U(a1);
      i32x8 B0 = SHUF8U(b[cs][p][0]), B1 = SHUF8U(b[cs][p][1]);
      __builtin_amdgcn_s_setprio(1);
      MFMA1(A0, B0, 0, 0);
      MFMA1(A0, B1, 0, 1);
      MFMA1(A1, B0, 1, 0);
      MFMA1(A1, B1, 1, 1);
      __builtin_amdgcn_s_setprio(0);
    }
  }

  __syncthreads();   // full drain once; reuse smem for epilogue

  // Epilogue (verified rounds 0-11): wave-private 8KB, stride-68 col-major.
  float* Ep = (float*)(smem + wave * 8192);
  const int h = lane >> 5;
  const int c = lane & 31;
  float tot = 0.0f;
#pragma unroll
  for (int pp = 0; pp < 2; ++pp) {
    if ((c >> 4) == pp) {
      const int colbase = (c & 15) * 68;
#pragma unroll
      for (int mt = 0; mt < 2; ++mt) {
#pragma unroll
        for (int g = 0; g < 4; ++g) {
          f32x4 v;
#pragma unroll
          for (int e = 0; e < 4; ++e) {
            const int r = g * 4 + e;
            v[e] = __expf(acc[mt][0][r] * INV_S2) + __expf(acc[mt][1][r] * INV_S2);
          }
          *(f32x4*)(Ep + colbase + mt * 32 + g * 8 + h * 4) = v;  // row = mt*32+8g+4h+e
        }
      }
    }
#pragma unroll
    for (int cc = 0; cc < 16; ++cc)
      tot += Ep[cc * 68 + lane];
  }
  atomicAdd(&g_S[(size_t)bm * BM + (wave >> 1) * 64 + lane], tot);
}

// loss = sum_t log(S_t) - T_t
__global__ __launch_bounds__(1024) void mevo_finalize(float* __restrict__ out) {
  __shared__ float red[16];
  const int tid = threadIdx.x;
  float local = 0.0f;
  for (int t = tid; t < TOKENS; t += 1024)
    local += __logf(g_S[t]) - g_T[t];
#pragma unroll
  for (int m = 1; m <= 32; m <<= 1) local += __shfl_xor(local, m);
  if ((tid & 63) == 0) red[tid >> 6] = local;
  __syncthreads();
  if (tid < 16) {
    float v = red[tid];
    v += __shfl_xor(v, 1);
    v += __shfl_xor(v, 2);
    v += __shfl_xor(v, 4);
    v += __shfl_xor(v, 8);
    if (tid == 0) out[0] = v;
  }
}

extern "C" void kernel_launch(void* const* d_in, const int* in_sizes, int n_in,
                              void* d_out, int out_size, void* d_ws, size_t ws_size,
                              hipStream_t stream) {
  const float* X      = (const float*)d_in[0];
  const float* W      = (const float*)d_in[1];
  const int*   target = (const int*)d_in[2];
  float*       out    = (float*)d_out;

  cvt_tscore<<<CVT_BLOCKS + TSC_BLOCKS, 256, 0, stream>>>(
      (const float4*)X, (const float4*)W, target);
  mevo_gemm<<<(TOKENS / BM) * (VOCAB / BN), 256, 0, stream>>>();
  mevo_finalize<<<1, 1024, 0, stream>>>(out);
}

// Round 13
// 375.417 us; speedup vs baseline: 1.2156x; 1.2156x over previous
//
#include <hip/hip_runtime.h>
#include <stdint.h>

#define TOKENS 8192
#define DM     1024
#define VOCAB  32000
#define BM     128
#define BN     128
#define NITER  8            // 8 iters x 2 k-blocks of 64 (K = 1024)

#define SCALE   64.0f
#define INV_S2  2.44140625e-4f   // 1/(SCALE*SCALE)
#define A_BYTES ((size_t)TOKENS * DM / 2)

#define CVT_BLOCKS ((TOKENS + VOCAB) * (DM / 32) / 256)   // 5024
#define TSC_BLOCKS (TOKENS / 4)                           // 2048

typedef int   i32x4  __attribute__((ext_vector_type(4)));
typedef int   i32x8  __attribute__((ext_vector_type(8)));
typedef float f32x4  __attribute__((ext_vector_type(4)));
typedef float f32x16 __attribute__((ext_vector_type(16)));

// g_P4: x then W in fp4 e2m1 (scaled x64), tiled slot-order layout.
// For 32-row group R, 64-k block K, slot u in [0,64):
//   chunk addr = R*16384 + K*1024 + u*16 bytes, u = h*32 + r
//   content    = row R*32+r, k-elements [K*64 + h*32, +32), nibble j = element j
// Verified (absmax 0, rounds 0-12). Chunks are lane-linear: a direct
// global_load_dwordx4 IS an MFMA fragment; contiguous copy IS LDS staging.
//
// r12 lesson: depth-2 on both operands needs ~132 regs; launch_bounds(256,4)
// caps at 128 -> whole b array demoted to scratch (VGPR=64, WRITE 551MB).
// This round: identical kernel at launch_bounds(256,3) (budget ~168, 12
// waves/CU) -- the first VALID test of the latency-equilibrium theory:
// 6 loads pinned in flight across every barrier, 2-iter issue-to-use
// distance on BOTH operands.
__device__ __align__(16) unsigned char g_P4[(size_t)(TOKENS + VOCAB) * DM / 2];
__device__ float g_S[TOKENS];   // sum exp(logit); logits ~ +-0.1 -> no max shift
__device__ float g_T[TOKENS];   // target score (exact fp32)

// Fallback RTN to e2m1 grid {0,.5,1,1.5,2,3,4,6} after x64 scale.
__device__ __forceinline__ unsigned q4(float x) {
  float a = fabsf(x) * SCALE;
  unsigned n = (unsigned)(a >= 0.25f) + (a >= 0.75f) + (a >= 1.25f) + (a >= 1.75f)
             + (a >= 2.5f) + (a >= 3.5f) + (a >= 5.0f);
  return n | ((x < 0.0f) ? 8u : 0u);
}

#if __has_builtin(__builtin_amdgcn_cvt_scalef32_pk_fp4_f32)
// HW path (verified r7-r12, absmax 0): one VALU op packs 2 f32 -> 2 e2m1 nibbles.
__device__ __forceinline__ unsigned pk8(const float4 a, const float4 b) {
  unsigned w = 0;
  w = __builtin_amdgcn_cvt_scalef32_pk_fp4_f32(w, a.x * SCALE, a.y * SCALE, 1.0f, 0);
  w = __builtin_amdgcn_cvt_scalef32_pk_fp4_f32(w, a.z * SCALE, a.w * SCALE, 1.0f, 1);
  w = __builtin_amdgcn_cvt_scalef32_pk_fp4_f32(w, b.x * SCALE, b.y * SCALE, 1.0f, 2);
  w = __builtin_amdgcn_cvt_scalef32_pk_fp4_f32(w, b.z * SCALE, b.w * SCALE, 1.0f, 3);
  return w;
}
#else
__device__ __forceinline__ unsigned pk8(const float4 a, const float4 b) {
  return  q4(a.x)        | (q4(a.y) << 4)  | (q4(a.z) << 8)  | (q4(a.w) << 12)
       | (q4(b.x) << 16) | (q4(b.y) << 20) | (q4(b.z) << 24) | (q4(b.w) << 28);
}
#endif

// Fused cvt_fp4 + tscore (independent inputs; verified r6-r12). Blocks
// [0, CVT_BLOCKS) = cvt; [CVT_BLOCKS, +TSC_BLOCKS) = tscore.
__global__ __launch_bounds__(256) void cvt_tscore(const float4* __restrict__ X,
                                                  const float4* __restrict__ W,
                                                  const int* __restrict__ target) {
  if (blockIdx.x < CVT_BLOCKS) {
    // Thread = one 16B output chunk = 32 consecutive input floats (128B
    // contiguous read, fully-sequential 16B write). Also zeroes g_S.
    const unsigned c  = blockIdx.x * 256 + threadIdx.x;      // global chunk idx
    const unsigned AC = (unsigned)TOKENS * (DM / 32);        // 262144 A-chunks
    const float4* src;
    unsigned lc;
    if (c < AC) { src = X; lc = c; } else { src = W; lc = c - AC; }
    const unsigned R  = lc >> 10;          // 1024 chunks per 32-row group
    const unsigned kb = (lc >> 6) & 15;    // k-block
    const unsigned u  = lc & 63;
    const unsigned row = R * 32 + (u & 31);
    const float4* p = src + (size_t)row * (DM / 4) + kb * 16 + (u >> 5) * 8;
    uint4 r;
    r.x = pk8(p[0], p[1]);
    r.y = pk8(p[2], p[3]);
    r.z = pk8(p[4], p[5]);
    r.w = pk8(p[6], p[7]);
    ((uint4*)g_P4)[c] = r;
    if (c < TOKENS) g_S[c] = 0.0f;
  } else {
    // tscore (verified rounds 0-12): one wave per token, exact fp32.
    const int wave  = threadIdx.x >> 6;
    const int lane  = threadIdx.x & 63;
    const int token = (blockIdx.x - CVT_BLOCKS) * 4 + wave;
    const int tgt   = target[token];
    const float* Xs = (const float*)X;
    const float* Ws = (const float*)W;
    const float4* xr = (const float4*)(Xs + (size_t)token * DM);
    const float4* wr = (const float4*)(Ws + (size_t)tgt * DM);
    float acc = 0.0f;
#pragma unroll
    for (int i = 0; i < 4; ++i) {
      float4 a = xr[i * 64 + lane];
      float4 b = wr[i * 64 + lane];
      acc += a.x * b.x + a.y * b.y + a.z * b.z + a.w * b.w;
    }
#pragma unroll
    for (int m = 1; m <= 32; m <<= 1) acc += __shfl_xor(acc, m);
    if (lane == 0) g_T[token] = acc;
  }
}

// MX-fp4 GEMM: 128x128 block, 4 waves of 64x64 (2x2 of 32x32),
// mfma_scale_f32_32x32x64_f8f6f4 FMT=fp4 (unit scales).
// Split-pipe delivery (r10) + DEPTH-2 pinned pipeline on BOTH operands:
//   A: LDS triple-buffer via global_load_lds, staged 2 iters ahead.
//   B: 3 rotating register slots, loaded 2 iters ahead (asm-pinned order).
//   Per iter: raw s_barrier + s_waitcnt vmcnt(6) -- outstanding oldest->
//   newest = [B(it)4, A(it)2, B(it+1)4, A(it+1)2]; retire oldest 6, keep
//   6 in flight across the barrier. Full drain only at the last iter.
// launch_bounds(256,3): reg budget ~168 so acc(64)+b(48)+misc fits in
// registers (r12's (256,4)=128 cap demoted b to scratch). 3 blocks/CU.
__global__ __launch_bounds__(256, 3) void mevo_gemm() {
  // [0,24K): A triple-buffer (3 x 4 groups x 2 kb x 1KB).
  // Epilogue reuses all 32KB (4 x 8KB wave-private) after the final barrier.
  __shared__ __align__(16) unsigned char smem[32768];

  const int tid  = threadIdx.x;
  const int wave = tid >> 6;
  const int lane = tid & 63;

  const int bm = blockIdx.x & 63;    // consecutive blocks share bn -> B L2 reuse
  const int bn = blockIdx.x >> 6;    // (natural order is XCD-optimal: XCD=bm%8)

  const int tAbase = (wave >> 1) * 2;   // wave's two 32-row A groups
  const int tBbase = (wave & 1) * 2;    // wave's two 32-col B groups

  // A staging source: thread covers group tid>>6, slot tid&63 (contiguous
  // copy; LDS dst = wave-uniform base + lane*16 as gload_lds requires).
  const unsigned char* sA = g_P4 + ((size_t)(bm * 4 + (tid >> 6)) << 14) + (tid & 63) * 16;
  // B fragment streams (lane-linear, coalesced).
  const unsigned char* pB0 = g_P4 + A_BYTES + ((size_t)(bn * 4 + tBbase) << 14) + lane * 16;
  const unsigned char* pB1 = pB0 + 16384;

  f32x16 acc[2][2] = {};

#define STAGE_A(buf, koff)                                                          \
  do {                                                                              \
    unsigned char* lb = smem + (buf) * 8192;                                        \
    __builtin_amdgcn_global_load_lds(                                               \
        (const __attribute__((address_space(1))) void*)(sA + (koff)),               \
        (__attribute__((address_space(3))) void*)(lb + tid * 16), 16, 0, 0);        \
    __builtin_amdgcn_global_load_lds(                                               \
        (const __attribute__((address_space(1))) void*)(sA + (koff) + 1024),        \
        (__attribute__((address_space(3))) void*)(lb + 4096 + tid * 16), 16, 0, 0); \
  } while (0)

#define LOAD_B(slot, koff)                                                  \
  do {                                                                      \
    b[slot][0][0] = *(const i32x4*)(pB0 + (koff));                          \
    b[slot][0][1] = *(const i32x4*)(pB1 + (koff));                          \
    b[slot][1][0] = *(const i32x4*)(pB0 + (koff) + 1024);                   \
    b[slot][1][1] = *(const i32x4*)(pB1 + (koff) + 1024);                   \
  } while (0)

// undef-hi operand widen: fp4 (cbsz/blgp=4) reads only regs 0-3 of the 8-reg
// operand; undef hi lets regalloc alias without dup v_movs.
#define SHUF8U(v) __builtin_shufflevector((v), (v), 0, 1, 2, 3, -1, -1, -1, -1)
#define MFMA1(Av, Bv, mt, nt)                                               \
  acc[mt][nt] = __builtin_amdgcn_mfma_scale_f32_32x32x64_f8f6f4(            \
      (Av), (Bv), acc[mt][nt], 4, 4, 0, 0x7F7F7F7F, 0, 0x7F7F7F7F)

  i32x4 b[3][2][2];   // [slot][kb-parity][nt]; static after full unroll

  // Prologue, issue order PINNED: B(0), A(0), B(1), A(1) -> outstanding
  // oldest->newest = [B0 x4, A0 x2, B1 x4, A1 x2] (12 loads).
  LOAD_B(0, 0);
  asm volatile("" ::: "memory");
  STAGE_A(0, 0);
  asm volatile("" ::: "memory");
  LOAD_B(1, 2048);
  asm volatile("" ::: "memory");
  STAGE_A(1, 2048);

#pragma unroll
  for (int it = 0; it < NITER; ++it) {
    // Counted wait: retire B(it)+A(it) (oldest 6), keep B(it+1)+A(it+1)
    // (6 newest) in flight across the barrier. Steady state, prologue, and
    // tails (it=6: no new issues, 12 outstanding -> vmcnt(6) ok; it=7: only
    // 6 outstanding -> vmcnt(0) drains) verified by hand.
    if (it < NITER - 1) asm volatile("s_waitcnt vmcnt(6)" ::: "memory");
    else                asm volatile("s_waitcnt vmcnt(0)" ::: "memory");
    __builtin_amdgcn_s_barrier();
    asm volatile("" ::: "memory");

    // Issue iter it+2's loads: B FIRST, then A (order pinned so the vmcnt
    // arithmetic above stays valid).
    if (it + 2 < NITER) {
      LOAD_B((it + 2) % 3, (it + 2) * 2048);
      asm volatile("" ::: "memory");
      STAGE_A((it + 2) % 3, (it + 2) * 2048);
      asm volatile("" ::: "memory");
    }

    const unsigned char* Ab = smem + (it % 3) * 8192;
    const int cs = it % 3;
#pragma unroll
    for (int p = 0; p < 2; ++p) {
      i32x4 a0 = *(const i32x4*)(Ab + p * 4096 + (tAbase + 0) * 1024 + lane * 16);
      i32x4 a1 = *(const i32x4*)(Ab + p * 4096 + (tAbase + 1) * 1024 + lane * 16);
      i32x8 A0 = SHUF8U(a0), A1 = SHUF8U(a1);
      i32x8 B0 = SHUF8U(b[cs][p][0]), B1 = SHUF8U(b[cs][p][1]);
      __builtin_amdgcn_s_setprio(1);
      MFMA1(A0, B0, 0, 0);
      MFMA1(A0, B1, 0, 1);
      MFMA1(A1, B0, 1, 0);
      MFMA1(A1, B1, 1, 1);
      __builtin_amdgcn_s_setprio(0);
    }
  }

  __syncthreads();   // full drain once; reuse smem for epilogue

  // Epilogue (verified rounds 0-12): wave-private 8KB, stride-68 col-major.
  float* Ep = (float*)(smem + wave * 8192);
  const int h = lane >> 5;
  const int c = lane & 31;
  float tot = 0.0f;
#pragma unroll
  for (int pp = 0; pp < 2; ++pp) {
    if ((c >> 4) == pp) {
      const int colbase = (c & 15) * 68;
#pragma unroll
      for (int mt = 0; mt < 2; ++mt) {
#pragma unroll
        for (int g = 0; g < 4; ++g) {
          f32x4 v;
#pragma unroll
          for (int e = 0; e < 4; ++e) {
            const int r = g * 4 + e;
            v[e] = __expf(acc[mt][0][r] * INV_S2) + __expf(acc[mt][1][r] * INV_S2);
          }
          *(f32x4*)(Ep + colbase + mt * 32 + g * 8 + h * 4) = v;  // row = mt*32+8g+4h+e
        }
      }
    }
#pragma unroll
    for (int cc = 0; cc < 16; ++cc)
      tot += Ep[cc * 68 + lane];
  }
  atomicAdd(&g_S[(size_t)bm * BM + (wave >> 1) * 64 + lane], tot);
}

// loss = sum_t log(S_t) - T_t
__global__ __launch_bounds__(1024) void mevo_finalize(float* __restrict__ out) {
  __shared__ float red[16];
  const int tid = threadIdx.x;
  float local = 0.0f;
  for (int t = tid; t < TOKENS; t += 1024)
    local += __logf(g_S[t]) - g_T[t];
#pragma unroll
  for (int m = 1; m <= 32; m <<= 1) local += __shfl_xor(local, m);
  if ((tid & 63) == 0) red[tid >> 6] = local;
  __syncthreads();
  if (tid < 16) {
    float v = red[tid];
    v += __shfl_xor(v, 1);
    v += __shfl_xor(v, 2);
    v += __shfl_xor(v, 4);
    v += __shfl_xor(v, 8);
    if (tid == 0) out[0] = v;
  }
}

extern "C" void kernel_launch(void* const* d_in, const int* in_sizes, int n_in,
                              void* d_out, int out_size, void* d_ws, size_t ws_size,
                              hipStream_t stream) {
  const float* X      = (const float*)d_in[0];
  const float* W      = (const float*)d_in[1];
  const int*   target = (const int*)d_in[2];
  float*       out    = (float*)d_out;

  cvt_tscore<<<CVT_BLOCKS + TSC_BLOCKS, 256, 0, stream>>>(
      (const float4*)X, (const float4*)W, target);
  mevo_gemm<<<(TOKENS / BM) * (VOCAB / BN), 256, 0, stream>>>();
  mevo_finalize<<<1, 1024, 0, stream>>>(out);
}